// Round 7
// baseline (497.195 us; speedup 1.0000x reference)
//
#include <hip/hip_runtime.h>
#include <math.h>

#define BB 16
#define SS 1024
#define NF 5
#define DD 64
#define HH 8
#define HDIM 8
#define NLAYER 2
#define FFD 128
#define NQ 8
#define QLAY 3
#define NC 3
#define NSWEEP 8
#define BHS_TOT (BB * HH * SS)   // 131072 = 1<<17

// ---------------- embed + positional encoding + layer-0 QKV ----------------
__global__ __launch_bounds__(64) void k_embed_qkv(const float* __restrict__ x,
                                                  const float* __restrict__ Wemb,
                                                  const float* __restrict__ bemb,
                                                  const float* __restrict__ Wq, const float* __restrict__ bq,
                                                  const float* __restrict__ Wk, const float* __restrict__ bk,
                                                  const float* __restrict__ Wv, const float* __restrict__ bv,
                                                  float* __restrict__ h,
                                                  float* __restrict__ qg, float* __restrict__ kv) {
    __shared__ float hrow[4][DD];
    int d   = threadIdx.x;
    int bs0 = blockIdx.x * 4;
    float be = bemb[d];
    int i2 = d >> 1;
    float div = expf((float)(2 * i2) * (-9.210340371976184f / 64.0f));
#pragma unroll
    for (int r = 0; r < 4; ++r) {
        int bs = bs0 + r;
        int s  = bs & (SS - 1);
        const float* xr = x + bs * NF;
        float acc = be;
#pragma unroll
        for (int f = 0; f < NF; ++f) acc += xr[f] * Wemb[f * DD + d];
        float ang = (float)s * div;
        float pe = (d & 1) ? cosf(ang) : sinf(ang);
        acc += pe;
        hrow[r][d] = acc;
        h[bs * DD + d] = acc;
    }
    __syncthreads();
    float aq[4], ak[4], av[4];
    float bqv = bq[d], bkv = bk[d], bvv = bv[d];
#pragma unroll
    for (int r = 0; r < 4; ++r) { aq[r] = bqv; ak[r] = bkv; av[r] = bvv; }
#pragma unroll 4
    for (int i = 0; i < DD; ++i) {
        float wqv = Wq[i * DD + d], wkv = Wk[i * DD + d], wvv = Wv[i * DD + d];
#pragma unroll
        for (int r = 0; r < 4; ++r) {
            float hv = hrow[r][i];
            aq[r] += hv * wqv; ak[r] += hv * wkv; av[r] += hv * wvv;
        }
    }
    int hh = d >> 3, hd = d & 7;
#pragma unroll
    for (int r = 0; r < 4; ++r) {
        int bs = bs0 + r;
        int b = bs >> 10, s = bs & 1023;
        int bhs = ((b * HH + hh) << 10) | s;
        qg[bhs * 8 + hd]      = aq[r];
        kv[bhs * 16 + hd]     = ak[r];
        kv[bhs * 16 + 8 + hd] = av[r];
    }
}

// ---------------- attention: 4 rows/thread, t chunked for occupancy ----------
// scores = q.k/sqrt(8), |score| << 1 -> exp safe without max subtraction.
// Each chunk writes partial (sum p*v, sum p); combined in k_post.
__global__ __launch_bounds__(256) void k_attn(const float* __restrict__ qg,
                                              const float* __restrict__ kv,
                                              float* __restrict__ Apart,   // [nch][BHS][8]
                                              float* __restrict__ lpart,   // [nch][BHS]
                                              int nch) {
    int bh  = blockIdx.x;             // 0..127
    int ch  = blockIdx.y;             // 0..nch-1
    int tid = threadIdx.x;
    int cht = SS / nch;
    const float4* kvp = (const float4*)(kv + ((bh << 10) + ch * cht) * 16);
    float q[4][8], A[4][8], ls[4];
#pragma unroll
    for (int r = 0; r < 4; ++r) {
        int s = tid + 256 * r;
        const float4* qr = (const float4*)(qg + (((bh << 10) | s) << 3));
        float4 qa = qr[0], qc = qr[1];
        q[r][0]=qa.x*0.3535533906f; q[r][1]=qa.y*0.3535533906f;
        q[r][2]=qa.z*0.3535533906f; q[r][3]=qa.w*0.3535533906f;
        q[r][4]=qc.x*0.3535533906f; q[r][5]=qc.y*0.3535533906f;
        q[r][6]=qc.z*0.3535533906f; q[r][7]=qc.w*0.3535533906f;
        ls[r] = 0.f;
#pragma unroll
        for (int d = 0; d < 8; ++d) A[r][d] = 0.f;
    }
#pragma unroll 2
    for (int t = 0; t < cht; ++t) {
        float4 k0 = kvp[4*t],   k1 = kvp[4*t+1];
        float4 v0 = kvp[4*t+2], v1 = kvp[4*t+3];
#pragma unroll
        for (int r = 0; r < 4; ++r) {
            float sc = q[r][0]*k0.x + q[r][1]*k0.y + q[r][2]*k0.z + q[r][3]*k0.w
                     + q[r][4]*k1.x + q[r][5]*k1.y + q[r][6]*k1.z + q[r][7]*k1.w;
            float p = __expf(sc);
            ls[r] += p;
            A[r][0] += p*v0.x; A[r][1] += p*v0.y; A[r][2] += p*v0.z; A[r][3] += p*v0.w;
            A[r][4] += p*v1.x; A[r][5] += p*v1.y; A[r][6] += p*v1.z; A[r][7] += p*v1.w;
        }
    }
#pragma unroll
    for (int r = 0; r < 4; ++r) {
        int s = tid + 256 * r;
        int bhs = (bh << 10) | s;
        float* arow = Apart + (((size_t)ch << 17) + bhs) * 8;
        ((float4*)arow)[0] = make_float4(A[r][0], A[r][1], A[r][2], A[r][3]);
        ((float4*)arow)[1] = make_float4(A[r][4], A[r][5], A[r][6], A[r][7]);
        lpart[((size_t)ch << 17) + bhs] = ls[r];
    }
}

// ---------------- fused post-attention: combine + Oproj + LN1 + FFN + LN2 (+ next QKV)
// 128 threads, 4 rows/block. wave 0 (t=0..63) handles rows 0,1; wave 1 rows 2,3.
__global__ __launch_bounds__(128) void k_post(const float* __restrict__ Apart,
                                              const float* __restrict__ lpart,
                                              const float* __restrict__ Wo, const float* __restrict__ bo,
                                              const float* __restrict__ g1, const float* __restrict__ b1,
                                              const float* __restrict__ Wf1, const float* __restrict__ bf1,
                                              const float* __restrict__ Wf2, const float* __restrict__ bf2,
                                              const float* __restrict__ g2, const float* __restrict__ b2,
                                              float* __restrict__ h, int l, int nch,
                                              const float* __restrict__ Wq, const float* __restrict__ bq,
                                              const float* __restrict__ Wk, const float* __restrict__ bk,
                                              const float* __restrict__ Wv, const float* __restrict__ bv,
                                              float* __restrict__ qg, float* __restrict__ kv, int nextl) {
    __shared__ float orow[4][DD];
    __shared__ float h1s[4][DD];
    __shared__ float frow[4][FFD];
    int t    = threadIdx.x;
    int d    = t & 63;
    int half = t >> 6;
    int bs0  = blockIdx.x * 4;
    int hh = d >> 3, hd = d & 7;

    // ---- Phase A: combine attention partials ----
#pragma unroll
    for (int rr = 0; rr < 2; ++rr) {
        int r  = half * 2 + rr;
        int bs = bs0 + r;
        int b = bs >> 10, s = bs & 1023;
        int bhs = ((b * HH + hh) << 10) | s;
        float a = 0.f, lt = 0.f;
        for (int ch = 0; ch < nch; ++ch) {
            a  += Apart[(((size_t)ch << 17) + bhs) * 8 + hd];
            lt += lpart[((size_t)ch << 17) + bhs];
        }
        orow[r][d] = a / lt;
    }
    __syncthreads();

    // ---- Oproj + residual + LN1 ----
    const float* wo = Wo + l * DD * DD;
    {
        float bias = bo[l * DD + d];
        float acc0 = bias, acc1 = bias;
        int r0 = half * 2, r1 = r0 + 1;
#pragma unroll 4
        for (int i = 0; i < DD; ++i) {
            float wv = wo[i * DD + d];
            acc0 += orow[r0][i] * wv;
            acc1 += orow[r1][i] * wv;
        }
        float gg = g1[l * DD + d], bb = b1[l * DD + d];
        float accs[2] = {acc0, acc1};
#pragma unroll
        for (int rr = 0; rr < 2; ++rr) {
            int r = half * 2 + rr;
            float a = accs[rr] + h[(bs0 + r) * DD + d];
            float sum = a;
            for (int off = 32; off; off >>= 1) sum += __shfl_xor(sum, off);
            float mean = sum * (1.f / 64.f);
            float dx = a - mean;
            float vs = dx * dx;
            for (int off = 32; off; off >>= 1) vs += __shfl_xor(vs, off);
            float rstd = rsqrtf(vs * (1.f / 64.f) + 1e-5f);
            h1s[r][d] = dx * rstd * gg + bb;
        }
    }
    __syncthreads();

    // ---- FFN1 (relu): thread t = f index ----
    {
        const float* w = Wf1 + l * DD * FFD;
        float bv = bf1[l * FFD + t];
        float a0 = bv, a1 = bv, a2 = bv, a3 = bv;
#pragma unroll 4
        for (int i = 0; i < DD; ++i) {
            float wv = w[i * FFD + t];
            a0 += h1s[0][i]*wv; a1 += h1s[1][i]*wv;
            a2 += h1s[2][i]*wv; a3 += h1s[3][i]*wv;
        }
        frow[0][t] = fmaxf(a0, 0.f); frow[1][t] = fmaxf(a1, 0.f);
        frow[2][t] = fmaxf(a2, 0.f); frow[3][t] = fmaxf(a3, 0.f);
    }
    __syncthreads();

    // ---- FFN2 + residual + LN2 -> h ----
    {
        const float* w = Wf2 + l * FFD * DD;
        float bias = bf2[l * DD + d];
        float acc0 = bias, acc1 = bias;
        int r0 = half * 2, r1 = r0 + 1;
#pragma unroll 4
        for (int i = 0; i < FFD; ++i) {
            float wv = w[i * DD + d];
            acc0 += frow[r0][i] * wv;
            acc1 += frow[r1][i] * wv;
        }
        float gg = g2[l * DD + d], bb = b2[l * DD + d];
        float accs[2] = {acc0, acc1};
#pragma unroll
        for (int rr = 0; rr < 2; ++rr) {
            int r = half * 2 + rr;
            float a = accs[rr] + h1s[r][d];
            float sum = a;
            for (int off = 32; off; off >>= 1) sum += __shfl_xor(sum, off);
            float mean = sum * (1.f / 64.f);
            float dx = a - mean;
            float vs = dx * dx;
            for (int off = 32; off; off >>= 1) vs += __shfl_xor(vs, off);
            float rstd = rsqrtf(vs * (1.f / 64.f) + 1e-5f);
            float h2 = dx * rstd * gg + bb;
            h[(bs0 + r) * DD + d] = h2;
            orow[r][d] = h2;        // reuse orow as h2 stage for QKV
        }
    }
    if (nextl < 0) return;
    __syncthreads();

    // ---- next-layer QKV from h2 (in orow) ----
    {
        const float* wq = Wq + nextl * DD * DD;
        const float* wk = Wk + nextl * DD * DD;
        const float* wv = Wv + nextl * DD * DD;
        int r0 = half * 2, r1 = r0 + 1;
        float aq0 = bq[nextl * DD + d], aq1 = aq0;
        float ak0 = bk[nextl * DD + d], ak1 = ak0;
        float av0 = bv[nextl * DD + d], av1 = av0;
#pragma unroll 4
        for (int i = 0; i < DD; ++i) {
            float wqv = wq[i * DD + d], wkv = wk[i * DD + d], wvv = wv[i * DD + d];
            float h0 = orow[r0][i], h1 = orow[r1][i];
            aq0 += h0 * wqv; aq1 += h1 * wqv;
            ak0 += h0 * wkv; ak1 += h1 * wkv;
            av0 += h0 * wvv; av1 += h1 * wvv;
        }
        float aqs[2] = {aq0, aq1}, aks[2] = {ak0, ak1}, avs[2] = {av0, av1};
#pragma unroll
        for (int rr = 0; rr < 2; ++rr) {
            int bs = bs0 + half * 2 + rr;
            int b = bs >> 10, s = bs & 1023;
            int bhs = ((b * HH + hh) << 10) | s;
            qg[bhs * 8 + hd]      = aqs[rr];
            kv[bhs * 16 + hd]     = aks[rr];
            kv[bhs * 16 + 8 + hd] = avs[rr];
        }
    }
}

// ---------------- mean pool over sequence (8-way split) ----------------
__global__ __launch_bounds__(64) void k_pool(const float* __restrict__ h, float* __restrict__ pp) {
    int b = blockIdx.x, c = blockIdx.y, d = threadIdx.x;
    const float* hp = h + (b * SS + c * 128) * DD + d;
    float acc = 0.f;
#pragma unroll 8
    for (int s = 0; s < 128; ++s) acc += hp[s * DD];
    pp[(b * 8 + c) * DD + d] = acc;
}

// ---------------- MLP head -> angles ----------------
__global__ __launch_bounds__(64) void k_head(const float* __restrict__ pp,
                                             const float* __restrict__ Wp1, const float* __restrict__ bp1,
                                             const float* __restrict__ Wp2, const float* __restrict__ bp2,
                                             float* __restrict__ angles) {
    __shared__ float pool_s[DD];
    __shared__ float hid[32];
    int b = blockIdx.x; int t = threadIdx.x;
    float acc = 0.f;
#pragma unroll
    for (int c = 0; c < 8; ++c) acc += pp[(b * 8 + c) * DD + t];
    pool_s[t] = acc * (1.f / 1024.f);
    __syncthreads();
    if (t < 32) {
        float a = bp1[t];
        for (int i = 0; i < DD; ++i) a += pool_s[i] * Wp1[i * 32 + t];
        hid[t] = fmaxf(a, 0.f);
    }
    __syncthreads();
    if (t < NQ) {
        float a = bp2[t];
        for (int j = 0; j < 32; ++j) a += hid[j] * Wp2[j * NQ + t];
        angles[b * NQ + t] = tanhf(a) * 3.14159265358979f;
    }
}

// ---------------- quantum circuit + Z-exps + entanglement entropy ----------------
// One wave (64 threads) per batch. Amplitude index i = (r<<6)|lane, r=0..3.
// Wire w <-> bit (7-w). Bits 0..5 are lane bits, bits 6..7 are register bits.
__global__ __launch_bounds__(64) void k_quantum(const float* __restrict__ angles,
                                                 const float* __restrict__ qw,
                                                 float* __restrict__ out) {
    int b = blockIdx.x; int L = threadIdx.x;
    float ar[4], ai[4];
#pragma unroll
    for (int r = 0; r < 4; ++r) { ar[r] = 0.f; ai[r] = 0.f; }
    if (L == 0) ar[0] = 1.f;

    const float* ang = angles + b * NQ;
    for (int l = 0; l < QLAY; ++l) {
        // ---- RX(angles[w]) on each wire ----
#pragma unroll
        for (int w = 0; w < NQ; ++w) {
            int p = 7 - w;
            float half = 0.5f * ang[w];
            float c = cosf(half), s = sinf(half);
            if (p == 7) {
#pragma unroll
                for (int lo = 0; lo < 2; ++lo) {
                    int hi = lo + 2;
                    float r0=ar[lo], m0=ai[lo], r1=ar[hi], m1=ai[hi];
                    ar[lo] = c*r0 + s*m1;  ai[lo] = c*m0 - s*r1;
                    ar[hi] = c*r1 + s*m0;  ai[hi] = c*m1 - s*r0;
                }
            } else if (p == 6) {
#pragma unroll
                for (int base = 0; base < 4; base += 2) {
                    int lo = base, hi = base + 1;
                    float r0=ar[lo], m0=ai[lo], r1=ar[hi], m1=ai[hi];
                    ar[lo] = c*r0 + s*m1;  ai[lo] = c*m0 - s*r1;
                    ar[hi] = c*r1 + s*m0;  ai[hi] = c*m1 - s*r0;
                }
            } else {
                int mask = 1 << p;
#pragma unroll
                for (int r = 0; r < 4; ++r) {
                    float pre = __shfl_xor(ar[r], mask);
                    float pim = __shfl_xor(ai[r], mask);
                    float nr = c*ar[r] + s*pim;
                    float ni = c*ai[r] - s*pre;
                    ar[r] = nr; ai[r] = ni;
                }
            }
        }
        // ---- Rot(phi,theta,omega) on each wire ----
#pragma unroll
        for (int w = 0; w < NQ; ++w) {
            const float* p3 = qw + (l * NQ + w) * 3;
            float phi = p3[0], th = p3[1], om = p3[2];
            float ct = cosf(0.5f * th), st = sinf(0.5f * th);
            float al = 0.5f * (phi + om), be = 0.5f * (phi - om);
            float ca = cosf(al), sa = sinf(al), cb = cosf(be), sb = sinf(be);
            float u00r =  ct * ca, u00i = -ct * sa;
            float u01r = -st * cb, u01i = -st * sb;
            float u10r =  st * cb, u10i = -st * sb;
            float u11r =  ct * ca, u11i =  ct * sa;
            int p = 7 - w;
            if (p >= 6) {
#pragma unroll
                for (int pi_ = 0; pi_ < 2; ++pi_) {
                    int lo = (p == 7) ? pi_ : pi_ * 2;
                    int hi = (p == 7) ? pi_ + 2 : pi_ * 2 + 1;
                    float r0=ar[lo], m0=ai[lo], r1=ar[hi], m1=ai[hi];
                    ar[lo] = u00r*r0 - u00i*m0 + u01r*r1 - u01i*m1;
                    ai[lo] = u00r*m0 + u00i*r0 + u01r*m1 + u01i*r1;
                    ar[hi] = u10r*r0 - u10i*m0 + u11r*r1 - u11i*m1;
                    ai[hi] = u10r*m0 + u10i*r0 + u11r*m1 + u11i*r1;
                }
            } else {
                int mask = 1 << p;
                int bit = (L >> p) & 1;
                float car = bit ? u11r : u00r, cai = bit ? u11i : u00i;
                float cpr = bit ? u10r : u01r, cpi = bit ? u10i : u01i;
#pragma unroll
                for (int r = 0; r < 4; ++r) {
                    float pre = __shfl_xor(ar[r], mask);
                    float pim = __shfl_xor(ai[r], mask);
                    float nr = car*ar[r] - cai*ai[r] + cpr*pre - cpi*pim;
                    float ni = car*ai[r] + cai*ar[r] + cpr*pim + cpi*pre;
                    ar[r] = nr; ai[r] = ni;
                }
            }
        }
        // ---- ring CNOTs, w -> (w+1)%8 ----
        { float t0=ar[2]; ar[2]=ar[3]; ar[3]=t0; t0=ai[2]; ai[2]=ai[3]; ai[3]=t0; }
        ar[1]=__shfl_xor(ar[1],32); ai[1]=__shfl_xor(ai[1],32);
        ar[3]=__shfl_xor(ar[3],32); ai[3]=__shfl_xor(ai[3],32);
#pragma unroll
        for (int w = 2; w <= 6; ++w) {
            int pc = 7 - w, pt = 6 - w;
            int tm = 1 << pt;
            bool ctrl = (L >> pc) & 1;
#pragma unroll
            for (int r = 0; r < 4; ++r) {
                float swr = __shfl_xor(ar[r], tm);
                float swi = __shfl_xor(ai[r], tm);
                ar[r] = ctrl ? swr : ar[r];
                ai[r] = ctrl ? swi : ai[r];
            }
        }
        {
            bool ctrl = L & 1;
            float n0r = ctrl ? ar[2] : ar[0], n2r = ctrl ? ar[0] : ar[2];
            float n0i = ctrl ? ai[2] : ai[0], n2i = ctrl ? ai[0] : ai[2];
            float n1r = ctrl ? ar[3] : ar[1], n3r = ctrl ? ar[1] : ar[3];
            float n1i = ctrl ? ai[3] : ai[1], n3i = ctrl ? ai[1] : ai[3];
            ar[0]=n0r; ar[1]=n1r; ar[2]=n2r; ar[3]=n3r;
            ai[0]=n0i; ai[1]=n1i; ai[2]=n2i; ai[3]=n3i;
        }
    }

    // ---- <Z_w>, w=0..2 ----
    {
        float p0 = ar[0]*ar[0]+ai[0]*ai[0];
        float p1 = ar[1]*ar[1]+ai[1]*ai[1];
        float p2 = ar[2]*ar[2]+ai[2]*ai[2];
        float p3 = ar[3]*ar[3]+ai[3]*ai[3];
        float z0 = p0 + p1 - p2 - p3;
        float z1 = p0 - p1 + p2 - p3;
        float zs = p0 + p1 + p2 + p3;
        float z2 = (L & 32) ? -zs : zs;
#pragma unroll
        for (int off = 1; off < 64; off <<= 1) {
            z0 += __shfl_xor(z0, off);
            z1 += __shfl_xor(z1, off);
            z2 += __shfl_xor(z2, off);
        }
        if (L == 0) {
            out[b * NC + 0] = z0;
            out[b * NC + 1] = z1;
            out[b * NC + 2] = z2;
        }
    }

    // ---- M = psi.reshape(16,16); lane (rb<<4)|c holds rows 4rb..4rb+3 of col c
    __shared__ float2 Mb[256];
#pragma unroll
    for (int r = 0; r < 4; ++r) Mb[(r << 6) | L] = make_float2(ar[r], ai[r]);
    __syncthreads();
    int cidx = L & 15, rb = L >> 4;
    float gr[4], gi[4];
#pragma unroll
    for (int k = 0; k < 4; ++k) {
        float2 t = Mb[((rb * 4 + k) << 4) | cidx];
        gr[k] = t.x; gi[k] = t.y;
    }

    // ---- one-sided complex Jacobi: orthogonalize columns of M ----
    for (int sweep = 0; sweep < NSWEEP; ++sweep) {
        for (int rd = 0; rd < 15; ++rd) {
            int q;
            if (cidx == 15) q = rd;
            else {
                int u = cidx - rd; if (u < 0) u += 15;
                if (u == 0) q = 15;
                else { q = rd + 15 - u; if (q >= 15) q -= 15; }
            }
            int plane = (rb << 4) | q;
            float pgr[4], pgi[4];
#pragma unroll
            for (int k = 0; k < 4; ++k) {
                pgr[k] = __shfl(gr[k], plane);
                pgi[k] = __shfl(gi[k], plane);
            }
            bool amLo = cidx < q;
            float al = 0.f, be = 0.f, gre = 0.f, gim = 0.f;
#pragma unroll
            for (int k = 0; k < 4; ++k) {
                float xr = amLo ? gr[k] : pgr[k], xi = amLo ? gi[k] : pgi[k]; // g_p
                float yr = amLo ? pgr[k] : gr[k], yi = amLo ? pgi[k] : gi[k]; // g_q
                al += xr*xr + xi*xi;
                be += yr*yr + yi*yi;
                gre += xr*yr + xi*yi;
                gim += xr*yi - xi*yr;
            }
#pragma unroll
            for (int off = 16; off <= 32; off <<= 1) {
                al  += __shfl_xor(al, off);
                be  += __shfl_xor(be, off);
                gre += __shfl_xor(gre, off);
                gim += __shfl_xor(gim, off);
            }
            float g2 = gre*gre + gim*gim;
            float cth = 1.f, sth = 0.f, cph = 1.f, sph = 0.f;
            if (g2 > 1e-26f) {
                float gn = sqrtf(g2);
                float ginv = 1.f / gn;
                cph = gre * ginv; sph = -gim * ginv;   // conjugate phase
                float tau = (al - be) * (0.5f * ginv);
                float t = ((tau >= 0.f) ? 1.f : -1.f) / (fabsf(tau) + sqrtf(1.f + tau*tau));
                cth = rsqrtf(1.f + t*t);
                sth = t * cth;
            }
            float sgn = amLo ? sth : -sth;
#pragma unroll
            for (int k = 0; k < 4; ++k) {
                float Emr = cph*gr[k] - sph*gi[k];
                float Emi = cph*gi[k] + sph*gr[k];
                float Eor = cph*pgr[k] - sph*pgi[k];
                float Eoi = cph*pgi[k] + sph*pgr[k];
                float amr = amLo ? gr[k] : Emr;
                float ami = amLo ? gi[k] : Emi;
                float obr = amLo ? Eor : pgr[k];
                float obi = amLo ? Eoi : pgi[k];
                gr[k] = cth * amr + sgn * obr;
                gi[k] = cth * ami + sgn * obi;
            }
        }
    }

    float lam = 0.f;
#pragma unroll
    for (int k = 0; k < 4; ++k) lam += gr[k]*gr[k] + gi[k]*gi[k];
#pragma unroll
    for (int off = 16; off <= 32; off <<= 1) lam += __shfl_xor(lam, off);
    float ev = fminf(fmaxf(lam, 1e-10f), 1.0f);
    float term = -ev * logf(ev);
#pragma unroll
    for (int off = 1; off <= 8; off <<= 1) term += __shfl_xor(term, off);
    if (L == 0) out[BB * NC + b] = term;
}

extern "C" void kernel_launch(void* const* d_in, const int* in_sizes, int n_in,
                              void* d_out, int out_size, void* d_ws, size_t ws_size,
                              hipStream_t stream) {
    const float* x    = (const float*)d_in[0];
    const float* Wemb = (const float*)d_in[1];
    const float* bemb = (const float*)d_in[2];
    const float* Wq   = (const float*)d_in[3];
    const float* bq   = (const float*)d_in[4];
    const float* Wk   = (const float*)d_in[5];
    const float* bk   = (const float*)d_in[6];
    const float* Wv   = (const float*)d_in[7];
    const float* bv   = (const float*)d_in[8];
    const float* Wo   = (const float*)d_in[9];
    const float* bo   = (const float*)d_in[10];
    const float* ln1g = (const float*)d_in[11];
    const float* ln1b = (const float*)d_in[12];
    const float* ln2g = (const float*)d_in[13];
    const float* ln2b = (const float*)d_in[14];
    const float* Wf1  = (const float*)d_in[15];
    const float* bf1  = (const float*)d_in[16];
    const float* Wf2  = (const float*)d_in[17];
    const float* bf2  = (const float*)d_in[18];
    const float* Wp1  = (const float*)d_in[19];
    const float* bp1  = (const float*)d_in[20];
    const float* Wp2  = (const float*)d_in[21];
    const float* bp2  = (const float*)d_in[22];
    const float* qwts = (const float*)d_in[23];
    float* out = (float*)d_out;

    const size_t M = 1u << 20;           // 1M floats = B*S*D
    // nch chosen from ws_size (constant per session -> graph-safe).
    auto needF = [&](int nch) {
        return 4 * M + (size_t)nch * M + (size_t)nch * BHS_TOT + BB * 8 * DD + 256;
    };
    int nch = 2;
    if      (ws_size >= needF(8) * sizeof(float)) nch = 8;
    else if (ws_size >= needF(4) * sizeof(float)) nch = 4;

    float* ws     = (float*)d_ws;
    float* h      = ws;                  // [B,S,D]                       1M
    float* qg     = ws + 1 * M;          // [BH,S,8]                      1M
    float* kv     = ws + 2 * M;          // [BH,S,16] K,V interleaved     2M
    float* Apart  = ws + 4 * M;          // [nch][BHS][8]               nch*M
    float* lpart  = Apart + (size_t)nch * M;         // [nch][BHS]
    float* pp     = lpart + (size_t)nch * BHS_TOT;   // pool partials [16][8][64]
    float* angls  = pp + BB * 8 * DD;                // [B,NQ]

    k_embed_qkv<<<BB * SS / 4, 64, 0, stream>>>(x, Wemb, bemb, Wq, bq, Wk, bk, Wv, bv,
                                                h, qg, kv);
    for (int l = 0; l < NLAYER; ++l) {
        k_attn<<<dim3(BB * HH, nch), 256, 0, stream>>>(qg, kv, Apart, lpart, nch);
        int nextl = (l + 1 < NLAYER) ? (l + 1) : -1;
        k_post<<<BB * SS / 4, 128, 0, stream>>>(Apart, lpart, Wo, bo, ln1g, ln1b,
                                                Wf1, bf1, Wf2, bf2, ln2g, ln2b,
                                                h, l, nch, Wq, bq, Wk, bk, Wv, bv,
                                                qg, kv, nextl);
    }
    k_pool<<<dim3(BB, 8), 64, 0, stream>>>(h, pp);
    k_head<<<BB, 64, 0, stream>>>(pp, Wp1, bp1, Wp2, bp2, angls);
    k_quantum<<<BB, 64, 0, stream>>>(angls, qwts, out);
}

// Round 9
// 437.416 us; speedup vs baseline: 1.1367x; 1.1367x over previous
//
#include <hip/hip_runtime.h>
#include <math.h>

#define BB 16
#define SS 1024
#define NF 5
#define DD 64
#define HH 8
#define HDIM 8
#define NLAYER 2
#define FFD 128
#define NQ 8
#define QLAY 3
#define NC 3
#define NSWEEP 8
#define BHS_TOT (BB * HH * SS)   // 131072 = 1<<17

typedef __fp16 hf2 __attribute__((ext_vector_type(2)));
__device__ inline hf2 ash2(float f) { union { float f; hf2 h; } u; u.f = f; return u.h; }

// ---------------- embed + positional encoding ----------------
__global__ __launch_bounds__(64) void k_embed(const float* __restrict__ x,
                                              const float* __restrict__ Wemb,
                                              const float* __restrict__ bemb,
                                              float* __restrict__ h) {
    int bs = blockIdx.x;            // 0..B*S-1
    int s  = bs & (SS - 1);
    int d  = threadIdx.x;           // 0..63
    const float* xr = x + bs * NF;
    float acc = bemb[d];
#pragma unroll
    for (int f = 0; f < NF; ++f) acc += xr[f] * Wemb[f * DD + d];
    int i = d >> 1;
    float div = expf((float)(2 * i) * (-9.210340371976184f / 64.0f));
    float ang = (float)s * div;
    float pe = (d & 1) ? cosf(ang) : sinf(ang);
    h[bs * DD + d] = acc + pe;
}

// ---------------- fused q,k,v projection (4 rows/block; f16 packed out) -----
// qh: [BH,S][4 x h2]   q pairs over d, pre-scaled by 1/sqrt(8)
// kvh: per (bh,tp=t/2): 16 x h2 = { k_t0 d-pairs[4], k_t1 d-pairs[4], v[d]=(v_t0,v_t1)[8] }
__global__ __launch_bounds__(64) void k_qkv(const float* __restrict__ h,
                                            const float* __restrict__ Wq, const float* __restrict__ bq,
                                            const float* __restrict__ Wk, const float* __restrict__ bk,
                                            const float* __restrict__ Wv, const float* __restrict__ bv,
                                            hf2* __restrict__ qh, hf2* __restrict__ kvh, int l) {
    __shared__ float hrow[4][DD];
    int d   = threadIdx.x;
    int bs0 = blockIdx.x * 4;
#pragma unroll
    for (int r = 0; r < 4; ++r) hrow[r][d] = h[(bs0 + r) * DD + d];
    __syncthreads();
    const float* wq = Wq + l * DD * DD;
    const float* wk = Wk + l * DD * DD;
    const float* wv = Wv + l * DD * DD;
    float aq[4], ak[4], av[4];
    float bqv = bq[l * DD + d], bkv = bk[l * DD + d], bvv = bv[l * DD + d];
#pragma unroll
    for (int r = 0; r < 4; ++r) { aq[r] = bqv; ak[r] = bkv; av[r] = bvv; }
#pragma unroll 4
    for (int i = 0; i < DD; ++i) {
        float wqv = wq[i * DD + d], wkv = wk[i * DD + d], wvv = wv[i * DD + d];
#pragma unroll
        for (int r = 0; r < 4; ++r) {
            float hv = hrow[r][i];
            aq[r] += hv * wqv; ak[r] += hv * wkv; av[r] += hv * wvv;
        }
    }
    int hh = d >> 3, hd = d & 7;
    const float qs = 0.3535533906f;
    float aqp[4], akp[4];
#pragma unroll
    for (int r = 0; r < 4; ++r) { aqp[r] = __shfl_xor(aq[r], 1); akp[r] = __shfl_xor(ak[r], 1); }
    if ((hd & 1) == 0) {
#pragma unroll
        for (int r = 0; r < 4; ++r) {
            int bs = bs0 + r;
            int b = bs >> 10, s = bs & 1023;
            int bh = b * HH + hh;
            int bhs = (bh << 10) | s;
            qh[bhs * 4 + (hd >> 1)] = __builtin_amdgcn_cvt_pkrtz(aq[r] * qs, aqp[r] * qs);
            int tp = s >> 1, par = s & 1;
            kvh[(bh * 512 + tp) * 16 + par * 4 + (hd >> 1)] =
                __builtin_amdgcn_cvt_pkrtz(ak[r], akp[r]);
        }
    }
    // v pairs over t: rows (0,1) and (2,3) are consecutive s with even parity start
#pragma unroll
    for (int r = 0; r < 4; r += 2) {
        int bs = bs0 + r;
        int b = bs >> 10, s = bs & 1023;
        int bh = b * HH + hh;
        int tp = s >> 1;
        kvh[(bh * 512 + tp) * 16 + 8 + hd] = __builtin_amdgcn_cvt_pkrtz(av[r], av[r + 1]);
    }
}

// ---------------- attention: f16 dot2 math, 1 row/thread, t chunked ---------
// score = (q/sqrt8).k via 4 chained fdot2; p = exp(score); A_d += fdot2(p-pair, v-pair)
__global__ __launch_bounds__(256) void k_attn(const hf2* __restrict__ qh,
                                              const float4* __restrict__ kvh4,
                                              float* __restrict__ Apart,   // [nch][BHS][8]
                                              float* __restrict__ lpart,   // [nch][BHS]
                                              int nch) {
    int bh  = blockIdx.x;             // 0..127
    int sg  = blockIdx.y & 3;
    int ch  = blockIdx.y >> 2;
    int tid = threadIdx.x;
    int s   = sg * 256 + tid;
    int tpc = 512 / nch;              // t-pairs per chunk
    const float4* kp = kvh4 + (size_t)(bh * 512 + ch * tpc) * 4;
    float4 qv = ((const float4*)qh)[(bh << 10) | s];
    hf2 q01 = ash2(qv.x), q23 = ash2(qv.y), q45 = ash2(qv.z), q67 = ash2(qv.w);
    hf2 one2 = __builtin_amdgcn_cvt_pkrtz(1.f, 1.f);
    float ls = 0.f;
    float A[8] = {0,0,0,0,0,0,0,0};
#pragma unroll 2
    for (int t = 0; t < tpc; ++t) {
        float4 f0 = kp[4*t], f1 = kp[4*t+1], f2 = kp[4*t+2], f3 = kp[4*t+3];
        float sc0 = __builtin_amdgcn_fdot2(q67, ash2(f0.w),
                    __builtin_amdgcn_fdot2(q45, ash2(f0.z),
                    __builtin_amdgcn_fdot2(q23, ash2(f0.y),
                    __builtin_amdgcn_fdot2(q01, ash2(f0.x), 0.f, false), false), false), false);
        float sc1 = __builtin_amdgcn_fdot2(q67, ash2(f1.w),
                    __builtin_amdgcn_fdot2(q45, ash2(f1.z),
                    __builtin_amdgcn_fdot2(q23, ash2(f1.y),
                    __builtin_amdgcn_fdot2(q01, ash2(f1.x), 0.f, false), false), false), false);
        float p0 = __expf(sc0), p1 = __expf(sc1);
        hf2 pp = __builtin_amdgcn_cvt_pkrtz(p0, p1);
        ls   = __builtin_amdgcn_fdot2(pp, one2,       ls,   false);
        A[0] = __builtin_amdgcn_fdot2(pp, ash2(f2.x), A[0], false);
        A[1] = __builtin_amdgcn_fdot2(pp, ash2(f2.y), A[1], false);
        A[2] = __builtin_amdgcn_fdot2(pp, ash2(f2.z), A[2], false);
        A[3] = __builtin_amdgcn_fdot2(pp, ash2(f2.w), A[3], false);
        A[4] = __builtin_amdgcn_fdot2(pp, ash2(f3.x), A[4], false);
        A[5] = __builtin_amdgcn_fdot2(pp, ash2(f3.y), A[5], false);
        A[6] = __builtin_amdgcn_fdot2(pp, ash2(f3.z), A[6], false);
        A[7] = __builtin_amdgcn_fdot2(pp, ash2(f3.w), A[7], false);
    }
    int bhs = (bh << 10) | s;
    float* arow = Apart + (((size_t)ch << 17) + bhs) * 8;
    ((float4*)arow)[0] = make_float4(A[0], A[1], A[2], A[3]);
    ((float4*)arow)[1] = make_float4(A[4], A[5], A[6], A[7]);
    lpart[((size_t)ch << 17) + bhs] = ls;
}

// ---------------- attention combine + O projection + residual + layernorm ----
__global__ __launch_bounds__(64) void k_projln(const float* __restrict__ Apart,
                                               const float* __restrict__ lpart,
                                               const float* __restrict__ Wo, const float* __restrict__ bo,
                                               const float* __restrict__ g, const float* __restrict__ bp,
                                               float* __restrict__ h, int l, int nch) {
    __shared__ float orow[4][DD];
    int d   = threadIdx.x;
    int bs0 = blockIdx.x * 4;
    int hh = d >> 3, hd = d & 7;
#pragma unroll
    for (int r = 0; r < 4; ++r) {
        int bs = bs0 + r;
        int b = bs >> 10, s = bs & 1023;
        int bhs = ((b * HH + hh) << 10) | s;
        float a = 0.f, lt = 0.f;
        for (int ch = 0; ch < nch; ++ch) {
            a  += Apart[(((size_t)ch << 17) + bhs) * 8 + hd];
            lt += lpart[((size_t)ch << 17) + bhs];
        }
        orow[r][d] = a / lt;
    }
    __syncthreads();
    const float* w = Wo + l * DD * DD;
    float bias = bo[l * DD + d];
    float acc[4] = {bias, bias, bias, bias};
#pragma unroll 4
    for (int i = 0; i < DD; ++i) {
        float wv = w[i * DD + d];
        acc[0] += orow[0][i]*wv; acc[1] += orow[1][i]*wv;
        acc[2] += orow[2][i]*wv; acc[3] += orow[3][i]*wv;
    }
    float gg = g[l * DD + d], bb = bp[l * DD + d];
#pragma unroll
    for (int r = 0; r < 4; ++r) {
        int bs = bs0 + r;
        float a = acc[r] + h[bs * DD + d];
        float sum = a;
        for (int off = 32; off; off >>= 1) sum += __shfl_xor(sum, off);
        float mean = sum * (1.f / 64.f);
        float dx = a - mean;
        float vs = dx * dx;
        for (int off = 32; off; off >>= 1) vs += __shfl_xor(vs, off);
        float rstd = rsqrtf(vs * (1.f / 64.f) + 1e-5f);
        h[bs * DD + d] = dx * rstd * gg + bb;
    }
}

// ---------------- FFN layer 1 (relu), 4 rows/block ----------------
__global__ __launch_bounds__(128) void k_ffn1(const float* __restrict__ h,
                                              const float* __restrict__ W, const float* __restrict__ bias,
                                              float* __restrict__ ff, int l) {
    __shared__ float hrow[4][DD];
    int f   = threadIdx.x;
    int bs0 = blockIdx.x * 4;
#pragma unroll
    for (int e = f; e < 4 * DD; e += 128) ((float*)hrow)[e] = h[bs0 * DD + e];
    __syncthreads();
    const float* w = W + l * DD * FFD;
    float bv = bias[l * FFD + f];
    float acc[4] = {bv, bv, bv, bv};
#pragma unroll 4
    for (int i = 0; i < DD; ++i) {
        float wv = w[i * FFD + f];
        acc[0] += hrow[0][i]*wv; acc[1] += hrow[1][i]*wv;
        acc[2] += hrow[2][i]*wv; acc[3] += hrow[3][i]*wv;
    }
#pragma unroll
    for (int r = 0; r < 4; ++r) ff[(bs0 + r) * FFD + f] = fmaxf(acc[r], 0.f);
}

// ---------------- FFN layer 2 + residual + layernorm, 4 rows/block ----------
__global__ __launch_bounds__(64) void k_ffn2ln(const float* __restrict__ ff,
                                               const float* __restrict__ W, const float* __restrict__ bias,
                                               const float* __restrict__ g, const float* __restrict__ bp,
                                               float* __restrict__ h, int l) {
    __shared__ float frow[4][FFD];
    int d   = threadIdx.x;
    int bs0 = blockIdx.x * 4;
#pragma unroll
    for (int e = d; e < 4 * FFD; e += 64) ((float*)frow)[e] = ff[bs0 * FFD + e];
    __syncthreads();
    const float* w = W + l * FFD * DD;
    float bv = bias[l * DD + d];
    float acc[4] = {bv, bv, bv, bv};
#pragma unroll 4
    for (int i = 0; i < FFD; ++i) {
        float wv = w[i * DD + d];
        acc[0] += frow[0][i]*wv; acc[1] += frow[1][i]*wv;
        acc[2] += frow[2][i]*wv; acc[3] += frow[3][i]*wv;
    }
    float gg = g[l * DD + d], bb = bp[l * DD + d];
#pragma unroll
    for (int r = 0; r < 4; ++r) {
        int bs = bs0 + r;
        float a = acc[r] + h[bs * DD + d];
        float sum = a;
        for (int off = 32; off; off >>= 1) sum += __shfl_xor(sum, off);
        float mean = sum * (1.f / 64.f);
        float dx = a - mean;
        float vs = dx * dx;
        for (int off = 32; off; off >>= 1) vs += __shfl_xor(vs, off);
        float rstd = rsqrtf(vs * (1.f / 64.f) + 1e-5f);
        h[bs * DD + d] = dx * rstd * gg + bb;
    }
}

// ---------------- mean pool over sequence (8-way split) ----------------
__global__ __launch_bounds__(64) void k_pool(const float* __restrict__ h, float* __restrict__ pp) {
    int b = blockIdx.x, c = blockIdx.y, d = threadIdx.x;
    const float* hp = h + (b * SS + c * 128) * DD + d;
    float acc = 0.f;
#pragma unroll 8
    for (int s = 0; s < 128; ++s) acc += hp[s * DD];
    pp[(b * 8 + c) * DD + d] = acc;
}

// ---------------- MLP head -> angles ----------------
__global__ __launch_bounds__(64) void k_head(const float* __restrict__ pp,
                                             const float* __restrict__ Wp1, const float* __restrict__ bp1,
                                             const float* __restrict__ Wp2, const float* __restrict__ bp2,
                                             float* __restrict__ angles) {
    __shared__ float pool_s[DD];
    __shared__ float hid[32];
    int b = blockIdx.x; int t = threadIdx.x;
    float acc = 0.f;
#pragma unroll
    for (int c = 0; c < 8; ++c) acc += pp[(b * 8 + c) * DD + t];
    pool_s[t] = acc * (1.f / 1024.f);
    __syncthreads();
    if (t < 32) {
        float a = bp1[t];
        for (int i = 0; i < DD; ++i) a += pool_s[i] * Wp1[i * 32 + t];
        hid[t] = fmaxf(a, 0.f);
    }
    __syncthreads();
    if (t < NQ) {
        float a = bp2[t];
        for (int j = 0; j < 32; ++j) a += hid[j] * Wp2[j * NQ + t];
        angles[b * NQ + t] = tanhf(a) * 3.14159265358979f;
    }
}

// ---------------- quantum circuit + Z-exps + entanglement entropy ----------------
__global__ __launch_bounds__(64) void k_quantum(const float* __restrict__ angles,
                                                 const float* __restrict__ qw,
                                                 float* __restrict__ out) {
    int b = blockIdx.x; int L = threadIdx.x;
    float ar[4], ai[4];
#pragma unroll
    for (int r = 0; r < 4; ++r) { ar[r] = 0.f; ai[r] = 0.f; }
    if (L == 0) ar[0] = 1.f;

    const float* ang = angles + b * NQ;
    for (int l = 0; l < QLAY; ++l) {
#pragma unroll
        for (int w = 0; w < NQ; ++w) {
            int p = 7 - w;
            float half = 0.5f * ang[w];
            float c = cosf(half), s = sinf(half);
            if (p == 7) {
#pragma unroll
                for (int lo = 0; lo < 2; ++lo) {
                    int hi = lo + 2;
                    float r0=ar[lo], m0=ai[lo], r1=ar[hi], m1=ai[hi];
                    ar[lo] = c*r0 + s*m1;  ai[lo] = c*m0 - s*r1;
                    ar[hi] = c*r1 + s*m0;  ai[hi] = c*m1 - s*r0;
                }
            } else if (p == 6) {
#pragma unroll
                for (int base = 0; base < 4; base += 2) {
                    int lo = base, hi = base + 1;
                    float r0=ar[lo], m0=ai[lo], r1=ar[hi], m1=ai[hi];
                    ar[lo] = c*r0 + s*m1;  ai[lo] = c*m0 - s*r1;
                    ar[hi] = c*r1 + s*m0;  ai[hi] = c*m1 - s*r0;
                }
            } else {
                int mask = 1 << p;
#pragma unroll
                for (int r = 0; r < 4; ++r) {
                    float pre = __shfl_xor(ar[r], mask);
                    float pim = __shfl_xor(ai[r], mask);
                    float nr = c*ar[r] + s*pim;
                    float ni = c*ai[r] - s*pre;
                    ar[r] = nr; ai[r] = ni;
                }
            }
        }
#pragma unroll
        for (int w = 0; w < NQ; ++w) {
            const float* p3 = qw + (l * NQ + w) * 3;
            float phi = p3[0], th = p3[1], om = p3[2];
            float ct = cosf(0.5f * th), st = sinf(0.5f * th);
            float al = 0.5f * (phi + om), be = 0.5f * (phi - om);
            float ca = cosf(al), sa = sinf(al), cb = cosf(be), sb = sinf(be);
            float u00r =  ct * ca, u00i = -ct * sa;
            float u01r = -st * cb, u01i = -st * sb;
            float u10r =  st * cb, u10i = -st * sb;
            float u11r =  ct * ca, u11i =  ct * sa;
            int p = 7 - w;
            if (p >= 6) {
#pragma unroll
                for (int pi_ = 0; pi_ < 2; ++pi_) {
                    int lo = (p == 7) ? pi_ : pi_ * 2;
                    int hi = (p == 7) ? pi_ + 2 : pi_ * 2 + 1;
                    float r0=ar[lo], m0=ai[lo], r1=ar[hi], m1=ai[hi];
                    ar[lo] = u00r*r0 - u00i*m0 + u01r*r1 - u01i*m1;
                    ai[lo] = u00r*m0 + u00i*r0 + u01r*m1 + u01i*r1;
                    ar[hi] = u10r*r0 - u10i*m0 + u11r*r1 - u11i*m1;
                    ai[hi] = u10r*m0 + u10i*r0 + u11r*m1 + u11i*r1;
                }
            } else {
                int mask = 1 << p;
                int bit = (L >> p) & 1;
                float car = bit ? u11r : u00r, cai = bit ? u11i : u00i;
                float cpr = bit ? u10r : u01r, cpi = bit ? u10i : u01i;
#pragma unroll
                for (int r = 0; r < 4; ++r) {
                    float pre = __shfl_xor(ar[r], mask);
                    float pim = __shfl_xor(ai[r], mask);
                    float nr = car*ar[r] - cai*ai[r] + cpr*pre - cpi*pim;
                    float ni = car*ai[r] + cai*ar[r] + cpr*pim + cpi*pre;
                    ar[r] = nr; ai[r] = ni;
                }
            }
        }
        { float t0=ar[2]; ar[2]=ar[3]; ar[3]=t0; t0=ai[2]; ai[2]=ai[3]; ai[3]=t0; }
        ar[1]=__shfl_xor(ar[1],32); ai[1]=__shfl_xor(ai[1],32);
        ar[3]=__shfl_xor(ar[3],32); ai[3]=__shfl_xor(ai[3],32);
#pragma unroll
        for (int w = 2; w <= 6; ++w) {
            int pc = 7 - w, pt = 6 - w;
            int tm = 1 << pt;
            bool ctrl = (L >> pc) & 1;
#pragma unroll
            for (int r = 0; r < 4; ++r) {
                float swr = __shfl_xor(ar[r], tm);
                float swi = __shfl_xor(ai[r], tm);
                ar[r] = ctrl ? swr : ar[r];
                ai[r] = ctrl ? swi : ai[r];
            }
        }
        {
            bool ctrl = L & 1;
            float n0r = ctrl ? ar[2] : ar[0], n2r = ctrl ? ar[0] : ar[2];
            float n0i = ctrl ? ai[2] : ai[0], n2i = ctrl ? ai[0] : ai[2];
            float n1r = ctrl ? ar[3] : ar[1], n3r = ctrl ? ar[1] : ar[3];
            float n1i = ctrl ? ai[3] : ai[1], n3i = ctrl ? ai[1] : ai[3];
            ar[0]=n0r; ar[1]=n1r; ar[2]=n2r; ar[3]=n3r;
            ai[0]=n0i; ai[1]=n1i; ai[2]=n2i; ai[3]=n3i;
        }
    }

    {
        float p0 = ar[0]*ar[0]+ai[0]*ai[0];
        float p1 = ar[1]*ar[1]+ai[1]*ai[1];
        float p2 = ar[2]*ar[2]+ai[2]*ai[2];
        float p3 = ar[3]*ar[3]+ai[3]*ai[3];
        float z0 = p0 + p1 - p2 - p3;
        float z1 = p0 - p1 + p2 - p3;
        float zs = p0 + p1 + p2 + p3;
        float z2 = (L & 32) ? -zs : zs;
#pragma unroll
        for (int off = 1; off < 64; off <<= 1) {
            z0 += __shfl_xor(z0, off);
            z1 += __shfl_xor(z1, off);
            z2 += __shfl_xor(z2, off);
        }
        if (L == 0) {
            out[b * NC + 0] = z0;
            out[b * NC + 1] = z1;
            out[b * NC + 2] = z2;
        }
    }

    __shared__ float2 Mb[256];
#pragma unroll
    for (int r = 0; r < 4; ++r) Mb[(r << 6) | L] = make_float2(ar[r], ai[r]);
    __syncthreads();
    int cidx = L & 15, rb = L >> 4;
    float gr[4], gi[4];
#pragma unroll
    for (int k = 0; k < 4; ++k) {
        float2 t = Mb[((rb * 4 + k) << 4) | cidx];
        gr[k] = t.x; gi[k] = t.y;
    }

    for (int sweep = 0; sweep < NSWEEP; ++sweep) {
        for (int rd = 0; rd < 15; ++rd) {
            int q;
            if (cidx == 15) q = rd;
            else {
                int u = cidx - rd; if (u < 0) u += 15;
                if (u == 0) q = 15;
                else { q = rd + 15 - u; if (q >= 15) q -= 15; }
            }
            int plane = (rb << 4) | q;
            float pgr[4], pgi[4];
#pragma unroll
            for (int k = 0; k < 4; ++k) {
                pgr[k] = __shfl(gr[k], plane);
                pgi[k] = __shfl(gi[k], plane);
            }
            bool amLo = cidx < q;
            float al = 0.f, be = 0.f, gre = 0.f, gim = 0.f;
#pragma unroll
            for (int k = 0; k < 4; ++k) {
                float xr = amLo ? gr[k] : pgr[k], xi = amLo ? gi[k] : pgi[k];
                float yr = amLo ? pgr[k] : gr[k], yi = amLo ? pgi[k] : gi[k];
                al += xr*xr + xi*xi;
                be += yr*yr + yi*yi;
                gre += xr*yr + xi*yi;
                gim += xr*yi - xi*yr;
            }
#pragma unroll
            for (int off = 16; off <= 32; off <<= 1) {
                al  += __shfl_xor(al, off);
                be  += __shfl_xor(be, off);
                gre += __shfl_xor(gre, off);
                gim += __shfl_xor(gim, off);
            }
            float g2 = gre*gre + gim*gim;
            float cth = 1.f, sth = 0.f, cph = 1.f, sph = 0.f;
            if (g2 > 1e-26f) {
                float gn = sqrtf(g2);
                float ginv = 1.f / gn;
                cph = gre * ginv; sph = -gim * ginv;   // conjugate phase
                float tau = (al - be) * (0.5f * ginv);
                float t = ((tau >= 0.f) ? 1.f : -1.f) / (fabsf(tau) + sqrtf(1.f + tau*tau));
                cth = rsqrtf(1.f + t*t);
                sth = t * cth;
            }
            float sgn = amLo ? sth : -sth;
#pragma unroll
            for (int k = 0; k < 4; ++k) {
                float Emr = cph*gr[k] - sph*gi[k];
                float Emi = cph*gi[k] + sph*gr[k];
                float Eor = cph*pgr[k] - sph*pgi[k];
                float Eoi = cph*pgi[k] + sph*pgr[k];
                float amr = amLo ? gr[k] : Emr;
                float ami = amLo ? gi[k] : Emi;
                float obr = amLo ? Eor : pgr[k];
                float obi = amLo ? Eoi : pgi[k];
                gr[k] = cth * amr + sgn * obr;
                gi[k] = cth * ami + sgn * obi;
            }
        }
    }

    float lam = 0.f;
#pragma unroll
    for (int k = 0; k < 4; ++k) lam += gr[k]*gr[k] + gi[k]*gi[k];
#pragma unroll
    for (int off = 16; off <= 32; off <<= 1) lam += __shfl_xor(lam, off);
    float ev = fminf(fmaxf(lam, 1e-10f), 1.0f);
    float term = -ev * logf(ev);
#pragma unroll
    for (int off = 1; off <= 8; off <<= 1) term += __shfl_xor(term, off);
    if (L == 0) out[BB * NC + b] = term;
}

extern "C" void kernel_launch(void* const* d_in, const int* in_sizes, int n_in,
                              void* d_out, int out_size, void* d_ws, size_t ws_size,
                              hipStream_t stream) {
    const float* x    = (const float*)d_in[0];
    const float* Wemb = (const float*)d_in[1];
    const float* bemb = (const float*)d_in[2];
    const float* Wq   = (const float*)d_in[3];
    const float* bq   = (const float*)d_in[4];
    const float* Wk   = (const float*)d_in[5];
    const float* bk   = (const float*)d_in[6];
    const float* Wv   = (const float*)d_in[7];
    const float* bv   = (const float*)d_in[8];
    const float* Wo   = (const float*)d_in[9];
    const float* bo   = (const float*)d_in[10];
    const float* ln1g = (const float*)d_in[11];
    const float* ln1b = (const float*)d_in[12];
    const float* ln2g = (const float*)d_in[13];
    const float* ln2b = (const float*)d_in[14];
    const float* Wf1  = (const float*)d_in[15];
    const float* bf1  = (const float*)d_in[16];
    const float* Wf2  = (const float*)d_in[17];
    const float* bf2  = (const float*)d_in[18];
    const float* Wp1  = (const float*)d_in[19];
    const float* bp1  = (const float*)d_in[20];
    const float* Wp2  = (const float*)d_in[21];
    const float* bp2  = (const float*)d_in[22];
    const float* qwts = (const float*)d_in[23];
    float* out = (float*)d_out;

    const size_t M = 1u << 20;           // 1M floats = B*S*D
    // float-unit sizes: h=1M, qh=0.5M, kvh=1M, ff=2M, Apart=nch*M, lpart=nch*BHS
    auto needF = [&](int nch) {
        return (size_t)(4.5 * M) + (size_t)nch * M + (size_t)nch * BHS_TOT + BB * 8 * DD + 256;
    };
    int nch = (ws_size >= needF(4) * sizeof(float)) ? 4 : 2;

    float* ws     = (float*)d_ws;
    float* h      = ws;                               // 1M
    hf2*   qh     = (hf2*)(ws + M);                   // 0.5M floats
    hf2*   kvh    = (hf2*)(ws + M + M / 2);           // 1M floats
    float* ff     = ws + (M * 5) / 2;                 // 2M
    float* Apart  = ws + (M * 9) / 2;                 // nch*M
    float* lpart  = Apart + (size_t)nch * M;          // nch*BHS_TOT
    float* pp     = lpart + (size_t)nch * BHS_TOT;    // [16][8][64]
    float* angls  = pp + BB * 8 * DD;                 // [B,NQ]

    k_embed<<<BB * SS, 64, 0, stream>>>(x, Wemb, bemb, h);
    for (int l = 0; l < NLAYER; ++l) {
        k_qkv<<<BB * SS / 4, 64, 0, stream>>>(h, Wq, bq, Wk, bk, Wv, bv, qh, kvh, l);
        k_attn<<<dim3(BB * HH, 4 * nch), 256, 0, stream>>>(qh, (const float4*)kvh, Apart, lpart, nch);
        k_projln<<<BB * SS / 4, 64, 0, stream>>>(Apart, lpart, Wo, bo, ln1g, ln1b, h, l, nch);
        k_ffn1<<<BB * SS / 4, 128, 0, stream>>>(h, Wf1, bf1, ff, l);
        k_ffn2ln<<<BB * SS / 4, 64, 0, stream>>>(ff, Wf2, bf2, ln2g, ln2b, h, l);
    }
    k_pool<<<dim3(BB, 8), 64, 0, stream>>>(h, pp);
    k_head<<<BB, 64, 0, stream>>>(pp, Wp1, bp1, Wp2, bp2, angls);
    k_quantum<<<BB, 64, 0, stream>>>(angls, qwts, out);
}